// Round 3
// baseline (741.843 us; speedup 1.0000x reference)
//
#include <hip/hip_runtime.h>
#include <cmath>

// Problem constants
#define Bb   64
#define Nn   1024
#define Wd   64
#define Rr   4
#define Cc   512
#define CINc 256
#define IFC  471   // R*W + R + W + 1 + 2*W + R + 2 + 3*R

// ---------- output offsets (floats) ----------
#define O_OUT    0          // 64*256
#define O_READS  16384      // 64*256
#define O_MEM    32768      // 64*1024*64
#define O_LINK   4227072    // 64*1024*1024
#define O_RW     71335936   // 64*4*1024
#define O_WW     71598080   // 64*1024
#define O_USAGE  71663616   // 64*1024
#define O_PREC   71729152   // 64*1024
#define O_CTRL   71794688   // 64*512
#define O_CNEW   71827456   // 64*512

// ---------- ws offsets (floats) ----------
#define W_GATES  0          // 64*2048
#define W_IFACE  131072     // 64*471
#define W_DER    161280     // 64*512
#define W_ALLOC  194048     // 64*1024
#define W_SCW    259584     // 64*1024
#define W_SCR    325120     // 64*4*1024
#define W_FWD    587264     // 64*4*1024
#define W_BWD    849408     // 64*4*1024

__device__ __forceinline__ float sigf_(float x){ return 1.0f/(1.0f+expf(-x)); }
__device__ __forceinline__ float softplusf_(float x){ return fmaxf(x,0.0f) + log1pf(expf(-fabsf(x))); }
__device__ __forceinline__ float waveSum_(float v){
  #pragma unroll
  for (int o=32;o;o>>=1) v += __shfl_xor(v,o);
  return v;
}
__device__ __forceinline__ float waveMax_(float v){
  #pragma unroll
  for (int o=32;o;o>>=1) v = fmaxf(v, __shfl_xor(v,o));
  return v;
}

// ---------------- K1: LSTM gates GEMM ----------------
// gates[b,o] = [x,read] . W_ih[o] + b_ih[o] + h . W_hh[o] + b_hh[o]
__global__ __launch_bounds__(256) void k_gates(
    const float* __restrict__ x, const float* __restrict__ rd,
    const float* __restrict__ h,
    const float* __restrict__ W_ih, const float* __restrict__ W_hh,
    const float* __restrict__ b_ih, const float* __restrict__ b_hh,
    float* __restrict__ gates)
{
  __shared__ __align__(16) float A1[512];
  __shared__ __align__(16) float A2[512];
  int b = blockIdx.y, t = threadIdx.x;
  for (int i=t;i<512;i+=256) A1[i] = (i<CINc)? x[b*CINc+i] : rd[b*256 + (i-CINc)];
  for (int i=t;i<512;i+=256) A2[i] = h[b*Cc+i];
  __syncthreads();
  int o = blockIdx.x*256 + t;
  const float4* w1 = reinterpret_cast<const float4*>(W_ih + (size_t)o*512);
  const float4* w2 = reinterpret_cast<const float4*>(W_hh + (size_t)o*Cc);
  const float4* a1 = reinterpret_cast<const float4*>(A1);
  const float4* a2 = reinterpret_cast<const float4*>(A2);
  float acc = b_ih[o] + b_hh[o];
  #pragma unroll 8
  for (int k=0;k<128;k++){ float4 w=w1[k], a=a1[k]; acc += w.x*a.x+w.y*a.y+w.z*a.z+w.w*a.w; }
  #pragma unroll 8
  for (int k=0;k<128;k++){ float4 w=w2[k], a=a2[k]; acc += w.x*a.x+w.y*a.y+w.z*a.z+w.w*a.w; }
  gates[(size_t)b*2048 + o] = acc;
}

// ---------------- K1b: LSTM pointwise ----------------
__global__ __launch_bounds__(256) void k_lstm_pt(
    const float* __restrict__ gates, const float* __restrict__ c_old,
    float* __restrict__ c_new, float* __restrict__ ctrl)
{
  int idx = blockIdx.x*256 + threadIdx.x;  // 64*512
  int b = idx >> 9, j = idx & 511;
  const float* g = gates + (size_t)b*2048;
  float ig = sigf_(g[j]);
  float fg = sigf_(g[512+j]);
  float gg = tanhf(g[1024+j]);
  float og = sigf_(g[1536+j]);
  float cn = fg*c_old[idx] + ig*gg;
  c_new[idx] = cn;
  ctrl[idx]  = og*tanhf(cn);
}

// ---------------- K2: iface GEMM ----------------
__global__ __launch_bounds__(256) void k_iface(
    const float* __restrict__ ctrl, const float* __restrict__ W_if,
    const float* __restrict__ b_if, float* __restrict__ iface)
{
  __shared__ __align__(16) float A[512];
  int b = blockIdx.y, t = threadIdx.x;
  for (int i=t;i<512;i+=256) A[i]=ctrl[b*Cc+i];
  __syncthreads();
  int o = blockIdx.x*256+t;
  if (o >= IFC) return;
  const float4* w = reinterpret_cast<const float4*>(W_if + (size_t)o*Cc);
  const float4* a = reinterpret_cast<const float4*>(A);
  float acc = b_if[o];
  #pragma unroll 8
  for (int k=0;k<128;k++){ float4 wv=w[k], av=a[k]; acc += wv.x*av.x+wv.y*av.y+wv.z*av.z+wv.w*av.w; }
  iface[(size_t)b*IFC + o] = acc;
}

// ---------------- K2b: parse iface into per-batch derived arrays ----------------
// Derived layout per batch (stride 512 floats):
// 0..3  sigf      4..7 rscale    8 wscale  9 ag  10 wg
// 12..23 modeP[r][k]
// 32..95 wk_unit  96..159 ev     160..223 wvec   224..479 rk_unit[r][w]
__global__ __launch_bounds__(64) void k_parse(
    const float* __restrict__ iface, float* __restrict__ der)
{
  int b = blockIdx.x, w = threadIdx.x;
  const float* f = iface + (size_t)b*IFC;
  float* D = der + (size_t)b*512;
  float wk = f[260+w];
  float wn = sqrtf(waveSum_(wk*wk)) + 1e-8f;
  D[32+w]  = wk/wn;
  D[96+w]  = sigf_(f[325+w]);   // ev = sigmoid(e_vec)
  D[160+w] = f[389+w];          // w_vec raw
  #pragma unroll
  for (int r=0;r<4;r++){
    float rk = f[r*64+w];
    float rn = sqrtf(waveSum_(rk*rk)) + 1e-8f;
    D[224 + r*64 + w] = rk/rn;
  }
  if (w < 4){
    D[w]   = sigf_(f[453+w]);                 // sigmoid(f_gates)
    D[4+w] = 1.0f + softplusf_(f[256+w]);     // read beta scale
    float m0=f[459+w*3], m1=f[459+w*3+1], m2=f[459+w*3+2];
    float mx = fmaxf(m0,fmaxf(m1,m2));
    float e0=expf(m0-mx), e1=expf(m1-mx), e2=expf(m2-mx);
    float s = e0+e1+e2;
    D[12+w*3]   = e0/s;
    D[12+w*3+1] = e1/s;
    D[12+w*3+2] = e2/s;
  }
  if (w == 0){
    D[8]  = 1.0f + softplusf_(f[324]);        // write beta scale
    D[9]  = sigf_(f[457]);                    // a_gate
    D[10] = sigf_(f[458]);                    // w_gate
  }
}

// ---------------- K3: usage update ----------------
__global__ __launch_bounds__(256) void k_usage(
    const float* __restrict__ der, const float* __restrict__ r_w,
    const float* __restrict__ usage, const float* __restrict__ w_w,
    float* __restrict__ usage_u)
{
  int idx = blockIdx.x*256+threadIdx.x;   // 64*1024
  int b = idx>>10, n = idx&1023;
  const float* D = der + (size_t)b*512;
  float ret = 1.0f;
  #pragma unroll
  for (int r=0;r<4;r++) ret *= (1.0f - D[r]*r_w[((size_t)b*4+r)*1024 + n]);
  float u = usage[idx], w = w_w[idx];
  usage_u[idx] = (u + w - u*w)*ret;
}

// ---------------- K3b: per-batch sort + allocation weighting ----------------
__global__ __launch_bounds__(1024) void k_sortalloc(
    const float* __restrict__ usage_u, float* __restrict__ alloc)
{
  __shared__ float sv[1024];
  __shared__ int   si[1024];
  __shared__ float sp[1024];
  int b = blockIdx.x, t = threadIdx.x;
  sv[t] = usage_u[b*1024+t];
  si[t] = t;
  __syncthreads();
  // bitonic sort ascending, stable via index tiebreak
  for (int k=2;k<=1024;k<<=1){
    for (int j=k>>1;j>0;j>>=1){
      int ixj = t ^ j;
      if (ixj > t){
        float a=sv[t], cc=sv[ixj];
        int ia=si[t], ic=si[ixj];
        bool up = ((t & k) == 0);
        bool gt = (a > cc) || (a==cc && ia > ic);
        if (up ? gt : !gt){ sv[t]=cc; sv[ixj]=a; si[t]=ic; si[ixj]=ia; }
      }
      __syncthreads();
    }
  }
  float myv = sv[t];
  sp[t] = myv;
  __syncthreads();
  // inclusive prefix product (matches jnp.cumprod)
  for (int off=1; off<1024; off<<=1){
    float pl = (t>=off)? sp[t-off] : 1.0f;
    float pm = sp[t];
    __syncthreads();
    sp[t] = pm*pl;
    __syncthreads();
  }
  alloc[b*1024 + si[t]] = (1.0f - myv)*sp[t];
}

// ---------------- K4: write-content scores ----------------
__global__ __launch_bounds__(256) void k_wscore(
    const float* __restrict__ mem, const float* __restrict__ der,
    float* __restrict__ scw)
{
  int t = threadIdx.x, lane = t&63;
  int row = blockIdx.x*4 + (t>>6);    // b*1024+n
  int b = row>>10;
  const float* D = der + (size_t)b*512;
  float m = mem[(size_t)row*64 + lane];
  float s1 = waveSum_(m * D[32+lane]);
  float s2 = waveSum_(m*m);
  if (lane==0) scw[row] = s1/(sqrtf(s2)+1e-8f) * D[8];
}

// ---------------- K4b: softmax -> ww, prec_new ----------------
__global__ __launch_bounds__(256) void k_wwprec(
    const float* __restrict__ scw, const float* __restrict__ alloc,
    const float* __restrict__ der, const float* __restrict__ prec,
    float* __restrict__ ww, float* __restrict__ prec_new)
{
  __shared__ float sred[4];
  int b = blockIdx.x, t = threadIdx.x;
  int wave=t>>6, lane=t&63;
  const float* D = der + (size_t)b*512;
  float ag = D[9], wg = D[10];
  float s[4];
  #pragma unroll
  for (int k=0;k<4;k++) s[k] = scw[b*1024 + t + k*256];
  float mx = fmaxf(fmaxf(s[0],s[1]),fmaxf(s[2],s[3]));
  mx = waveMax_(mx);
  if (lane==0) sred[wave]=mx;
  __syncthreads();
  mx = fmaxf(fmaxf(sred[0],sred[1]),fmaxf(sred[2],sred[3]));
  __syncthreads();
  float e[4], lsum=0.0f;
  #pragma unroll
  for (int k=0;k<4;k++){ e[k]=expf(s[k]-mx); lsum+=e[k]; }
  lsum = waveSum_(lsum);
  if (lane==0) sred[wave]=lsum;
  __syncthreads();
  float S = sred[0]+sred[1]+sred[2]+sred[3];
  __syncthreads();
  float wv[4], wsum=0.0f;
  #pragma unroll
  for (int k=0;k<4;k++){
    int n = t + k*256;
    float wc = e[k]/S;
    wv[k] = wg*(ag*alloc[b*1024+n] + (1.0f-ag)*wc);
    ww[b*1024+n] = wv[k];
    wsum += wv[k];
  }
  wsum = waveSum_(wsum);
  if (lane==0) sred[wave]=wsum;
  __syncthreads();
  float T = sred[0]+sred[1]+sred[2]+sred[3];
  #pragma unroll
  for (int k=0;k<4;k++){
    int n = t + k*256;
    prec_new[b*1024+n] = (1.0f-T)*prec[b*1024+n] + wv[k];
  }
}

// ---------------- K5: link update FUSED with fwd/bwd einsums ----------------
// block: 64 rows x 1024 cols of one batch; thread t owns cols [4t,4t+4)
__global__ __launch_bounds__(256) void k_link(
    const float* __restrict__ link, const float* __restrict__ ww,
    const float* __restrict__ prec, const float* __restrict__ r_w,
    float* __restrict__ link_new, float* __restrict__ fwd, float* __restrict__ bwd)
{
  __shared__ __align__(16) float sP[1024];
  __shared__ __align__(16) float sW[1024];
  __shared__ __align__(16) float sR[4][1024];
  __shared__ float fpart[64][4][4];   // [row][r][wave]
  int b = blockIdx.y, g = blockIdx.x, t = threadIdx.x;
  int wave = t>>6, lane = t&63;
  for (int i=t;i<1024;i+=256){ sP[i]=prec[b*1024+i]; sW[i]=ww[b*1024+i]; }
  for (int i=t;i<4096;i+=256) sR[i>>10][i&1023] = r_w[(size_t)b*4096 + i];
  __syncthreads();
  int j0 = t*4;
  float4 wwj4 = *reinterpret_cast<const float4*>(&sW[j0]);
  float4 pj4  = *reinterpret_cast<const float4*>(&sP[j0]);
  float wwj[4] = {wwj4.x,wwj4.y,wwj4.z,wwj4.w};
  float pj[4]  = {pj4.x,pj4.y,pj4.z,pj4.w};
  float rj[4][4];
  #pragma unroll
  for (int r=0;r<4;r++){
    float4 v = *reinterpret_cast<const float4*>(&sR[r][j0]);
    rj[r][0]=v.x; rj[r][1]=v.y; rj[r][2]=v.z; rj[r][3]=v.w;
  }
  float bacc[4][4] = {{0.f}};
  const size_t base = ((size_t)b*1024 + g*64)*1024;
  for (int il=0; il<64; il++){
    int i = g*64 + il;
    float wwi = sW[i];
    float4 L4 = *reinterpret_cast<const float4*>(&link[base + (size_t)il*1024 + j0]);
    float Lq[4] = {L4.x, L4.y, L4.z, L4.w};
    float Ln[4];
    #pragma unroll
    for (int q=0;q<4;q++){
      float v = (1.0f - wwi - wwj[q])*Lq[q] + wwi*pj[q];
      Ln[q] = (i == j0+q) ? 0.0f : v;     // zero diagonal
    }
    float4 st; st.x=Ln[0]; st.y=Ln[1]; st.z=Ln[2]; st.w=Ln[3];
    *reinterpret_cast<float4*>(&link_new[base + (size_t)il*1024 + j0]) = st;
    float rwi0 = sR[0][i], rwi1 = sR[1][i], rwi2 = sR[2][i], rwi3 = sR[3][i];
    #pragma unroll
    for (int q=0;q<4;q++){
      bacc[0][q] += Ln[q]*rwi0;
      bacc[1][q] += Ln[q]*rwi1;
      bacc[2][q] += Ln[q]*rwi2;
      bacc[3][q] += Ln[q]*rwi3;
    }
    #pragma unroll
    for (int r=0;r<4;r++){
      float fa = Ln[0]*rj[r][0]+Ln[1]*rj[r][1]+Ln[2]*rj[r][2]+Ln[3]*rj[r][3];
      fa = waveSum_(fa);
      if (lane==0) fpart[il][r][wave]=fa;
    }
  }
  __syncthreads();
  { // 256 threads = 64 rows x 4 r exactly
    int row = t>>2, r = t&3;
    fwd[((size_t)b*4+r)*1024 + g*64 + row] =
      fpart[row][r][0]+fpart[row][r][1]+fpart[row][r][2]+fpart[row][r][3];
  }
  #pragma unroll
  for (int r=0;r<4;r++)
    #pragma unroll
    for (int q=0;q<4;q++)
      atomicAdd(&bwd[((size_t)b*4+r)*1024 + j0 + q], bacc[r][q]);
}

// ---------------- K6: mem_new FUSED with read-content scores ----------------
__global__ __launch_bounds__(256) void k_memnew(
    const float* __restrict__ mem, const float* __restrict__ ww,
    const float* __restrict__ der, float* __restrict__ mem_new,
    float* __restrict__ scr)
{
  int t = threadIdx.x, lane=t&63;
  int row = blockIdx.x*4 + (t>>6);   // b*1024+n
  int b = row>>10, n = row&1023;
  const float* D = der + (size_t)b*512;
  float wwn = ww[row];
  float m = mem[(size_t)row*64+lane];
  float v = m*(1.0f - wwn*D[96+lane]) + wwn*D[160+lane];
  mem_new[(size_t)row*64+lane] = v;
  float nrm = sqrtf(waveSum_(v*v)) + 1e-8f;
  float d0 = waveSum_(v*D[224+lane]);
  float d1 = waveSum_(v*D[224+64+lane]);
  float d2 = waveSum_(v*D[224+128+lane]);
  float d3 = waveSum_(v*D[224+192+lane]);
  if (lane==0){
    scr[((size_t)b*4+0)*1024+n] = d0/nrm*D[4];
    scr[((size_t)b*4+1)*1024+n] = d1/nrm*D[5];
    scr[((size_t)b*4+2)*1024+n] = d2/nrm*D[6];
    scr[((size_t)b*4+3)*1024+n] = d3/nrm*D[7];
  }
}

// ---------------- K7: read softmax + mode mix -> rw_new ----------------
__global__ __launch_bounds__(256) void k_rc(
    const float* __restrict__ scr, const float* __restrict__ fwd,
    const float* __restrict__ bwd, const float* __restrict__ der,
    float* __restrict__ rw_new)
{
  __shared__ float sred[4];
  int br = blockIdx.x; int b = br>>2, r = br&3;
  int t = threadIdx.x, wave=t>>6, lane=t&63;
  const float* D = der + (size_t)b*512;
  float m0=D[12+r*3], m1=D[12+r*3+1], m2=D[12+r*3+2];
  float s[4];
  #pragma unroll
  for (int k=0;k<4;k++) s[k] = scr[(size_t)br*1024 + t + k*256];
  float mx = fmaxf(fmaxf(s[0],s[1]),fmaxf(s[2],s[3]));
  mx = waveMax_(mx);
  if (lane==0) sred[wave]=mx;
  __syncthreads();
  mx = fmaxf(fmaxf(sred[0],sred[1]),fmaxf(sred[2],sred[3]));
  __syncthreads();
  float e[4], lsum=0.0f;
  #pragma unroll
  for (int k=0;k<4;k++){ e[k]=expf(s[k]-mx); lsum+=e[k]; }
  lsum = waveSum_(lsum);
  if (lane==0) sred[wave]=lsum;
  __syncthreads();
  float S = sred[0]+sred[1]+sred[2]+sred[3];
  #pragma unroll
  for (int k=0;k<4;k++){
    size_t ix = (size_t)br*1024 + t + k*256;
    rw_new[ix] = m0*bwd[ix] + m1*(e[k]/S) + m2*fwd[ix];
  }
}

// ---------------- K8: reads = rw_new @ mem_new ----------------
__global__ __launch_bounds__(256) void k_reads(
    const float* __restrict__ rw_new, const float* __restrict__ mem_new,
    float* __restrict__ reads)
{
  __shared__ float sRW[4][256];
  __shared__ float red[4][4][64];   // [wave][r][lane]
  int chunk = blockIdx.x, b = blockIdx.y, t = threadIdx.x;
  int wave=t>>6, lane=t&63;
  for (int i=t;i<1024;i+=256)
    sRW[i>>8][i&255] = rw_new[(size_t)b*4096 + (size_t)(i>>8)*1024 + chunk*256 + (i&255)];
  __syncthreads();
  float acc0=0.f, acc1=0.f, acc2=0.f, acc3=0.f;
  int nbase = chunk*256 + wave*64;
  const float* mp = mem_new + ((size_t)b*1024 + nbase)*64 + lane;
  #pragma unroll 4
  for (int nn=0;nn<64;nn++){
    float v = mp[(size_t)nn*64];
    int nl = wave*64+nn;
    acc0 += sRW[0][nl]*v;
    acc1 += sRW[1][nl]*v;
    acc2 += sRW[2][nl]*v;
    acc3 += sRW[3][nl]*v;
  }
  red[wave][0][lane]=acc0; red[wave][1][lane]=acc1;
  red[wave][2][lane]=acc2; red[wave][3][lane]=acc3;
  __syncthreads();
  { int r=t>>6, l=t&63;
    float v = red[0][r][l]+red[1][r][l]+red[2][r][l]+red[3][r][l];
    atomicAdd(&reads[b*256 + r*64 + l], v); }
}

// ---------------- K9: output GEMM ----------------
__global__ __launch_bounds__(256) void k_out(
    const float* __restrict__ ctrl, const float* __restrict__ reads,
    const float* __restrict__ W_out, const float* __restrict__ b_out,
    float* __restrict__ out)
{
  __shared__ __align__(16) float A[768];
  int b = blockIdx.x, t = threadIdx.x;
  for (int i=t;i<768;i+=256) A[i] = (i<512)? ctrl[b*512+i] : reads[b*256 + (i-512)];
  __syncthreads();
  const float4* w = reinterpret_cast<const float4*>(W_out + (size_t)t*768);
  const float4* a = reinterpret_cast<const float4*>(A);
  float acc = b_out[t];
  #pragma unroll 8
  for (int k=0;k<192;k++){ float4 wv=w[k], av=a[k]; acc += wv.x*av.x+wv.y*av.y+wv.z*av.z+wv.w*av.w; }
  out[b*256+t] = acc;
}

extern "C" void kernel_launch(void* const* d_in, const int* in_sizes, int n_in,
                              void* d_out, int out_size, void* d_ws, size_t ws_size,
                              hipStream_t stream)
{
  const float* x      = (const float*)d_in[0];
  const float* rd     = (const float*)d_in[1];
  const float* h      = (const float*)d_in[2];
  const float* c      = (const float*)d_in[3];
  const float* mem    = (const float*)d_in[4];
  const float* link   = (const float*)d_in[5];
  const float* r_w    = (const float*)d_in[6];
  const float* w_w    = (const float*)d_in[7];
  const float* usage  = (const float*)d_in[8];
  const float* prec   = (const float*)d_in[9];
  const float* W_ih   = (const float*)d_in[10];
  const float* W_hh   = (const float*)d_in[11];
  const float* b_ih   = (const float*)d_in[12];
  const float* b_hh   = (const float*)d_in[13];
  const float* W_if   = (const float*)d_in[14];
  const float* b_if   = (const float*)d_in[15];
  const float* W_out  = (const float*)d_in[16];
  const float* b_out  = (const float*)d_in[17];

  float* out = (float*)d_out;
  float* o_out   = out + O_OUT;
  float* o_reads = out + O_READS;
  float* o_mem   = out + O_MEM;
  float* o_link  = out + O_LINK;
  float* o_rw    = out + O_RW;
  float* o_ww    = out + O_WW;
  float* o_usage = out + O_USAGE;
  float* o_prec  = out + O_PREC;
  float* o_ctrl  = out + O_CTRL;
  float* o_cnew  = out + O_CNEW;

  float* ws = (float*)d_ws;
  float* w_gates = ws + W_GATES;
  float* w_iface = ws + W_IFACE;
  float* w_der   = ws + W_DER;
  float* w_alloc = ws + W_ALLOC;
  float* w_scw   = ws + W_SCW;
  float* w_scr   = ws + W_SCR;
  float* w_fwd   = ws + W_FWD;
  float* w_bwd   = ws + W_BWD;

  // zero the atomic accumulators (ws/out are poisoned 0xAA before each call)
  hipMemsetAsync(w_bwd,   0, 262144*sizeof(float), stream);
  hipMemsetAsync(o_reads, 0, 16384*sizeof(float),  stream);

  k_gates   <<<dim3(8,64),  256, 0, stream>>>(x, rd, h, W_ih, W_hh, b_ih, b_hh, w_gates);
  k_lstm_pt <<<128,         256, 0, stream>>>(w_gates, c, o_cnew, o_ctrl);
  k_iface   <<<dim3(2,64),  256, 0, stream>>>(o_ctrl, W_if, b_if, w_iface);
  k_parse   <<<64,           64, 0, stream>>>(w_iface, w_der);
  k_usage   <<<256,         256, 0, stream>>>(w_der, r_w, usage, w_w, o_usage);
  k_sortalloc<<<64,        1024, 0, stream>>>(o_usage, w_alloc);
  k_wscore  <<<16384,       256, 0, stream>>>(mem, w_der, w_scw);
  k_wwprec  <<<64,          256, 0, stream>>>(w_scw, w_alloc, w_der, prec, o_ww, o_prec);
  k_link    <<<dim3(16,64), 256, 0, stream>>>(link, o_ww, prec, r_w, o_link, w_fwd, w_bwd);
  k_memnew  <<<16384,       256, 0, stream>>>(mem, o_ww, w_der, o_mem, w_scr);
  k_rc      <<<256,         256, 0, stream>>>(w_scr, w_fwd, w_bwd, w_der, o_rw);
  k_reads   <<<dim3(4,64),  256, 0, stream>>>(o_rw, o_mem, o_reads);
  k_out     <<<64,          256, 0, stream>>>(o_ctrl, o_reads, W_out, b_out, o_out);
}